// Round 5
// baseline (517.921 us; speedup 1.0000x reference)
//
#include <hip/hip_runtime.h>

#define HH 80
#define WW 80
#define HWN 6400
#define BN 16

typedef unsigned short ushortT;
typedef __attribute__((ext_vector_type(8))) short short8;
typedef __attribute__((ext_vector_type(4))) float f32x4;

static constexpr size_t BIGN = (size_t)BN * 64 * HWN;  // 6,553,600 floats

__device__ __forceinline__ float sigf(float v)  { return 1.f / (1.f + __expf(-v)); }
__device__ __forceinline__ float siluf(float v) { return v * sigf(v); }
__device__ __forceinline__ float bnap(float v, const float* __restrict__ bn, int c, int C) {
  float s = bn[c] * rsqrtf(bn[3 * C + c] + 1e-5f);
  return v * s + (bn[C + c] - bn[2 * C + c] * s);
}
__device__ __forceinline__ ushortT f2bf(float f) {  // RNE f32->bf16
  unsigned u = __float_as_uint(f);
  return (ushortT)((u + 0x7FFFu + ((u >> 16) & 1u)) >> 16);
}
__device__ __forceinline__ void gl_lds16(const void* g, void* l) {
  __builtin_amdgcn_global_load_lds(
      (const __attribute__((address_space(1))) unsigned int*)g,
      (__attribute__((address_space(3))) unsigned int*)l, 16, 0, 0);
}
// Bs LDS addressing: [p][k2] uints, row stride 20, 16B-chunk XOR swizzle.
__device__ __forceinline__ int bs_w(int p, int k2) {
  return p * 20 + ((((k2 >> 2) ^ ((p >> 3) & 3)) << 2) | (k2 & 3));
}
__device__ __forceinline__ int bs_r(int p, int q) {
  return p * 20 + (((q ^ ((p >> 3) & 3)) << 2));
}

// ---------------- K0: convert GEMM weights to bf16; zero cmean ---------------
__global__ __launch_bounds__(256) void k_cvtw(const float* __restrict__ wr,
    const float* __restrict__ we, const float* __restrict__ wp,
    ushortT* __restrict__ wrb, ushortT* __restrict__ web, ushortT* __restrict__ wpb,
    float* __restrict__ cmean) {
  int i = blockIdx.x * 256 + threadIdx.x;
  if (i < 32768) wrb[i] = f2bf(wr[i]);
  else if (i < 65536) web[i - 32768] = f2bf(we[i - 32768]);
  else if (i < 69632) wpb[i - 65536] = f2bf(wp[i - 65536]);
  if (i < 1024) cmean[i] = 0.f;
}

// ---------------- K1: MFMA GEMM 256->128 + BN + SiLU, fused transpose --------
// grid (50, 1, 16), block 256 (4 waves, each 64c x 64p); Ep aliased over As/Bs
__global__ __launch_bounds__(256) void k_reduce_mfma(
    const float* __restrict__ x, const ushortT* __restrict__ Wb,
    const float* __restrict__ bn, float* __restrict__ hs, float* __restrict__ hb) {
  __shared__ union {
    struct { ushortT As[128 * 32]; unsigned BsU[128 * 20]; } s;
    float Ep[4 * 16 * 68];
  } sm;
  const int t = threadIdx.x;
  const int w = t >> 6, l = t & 63;
  const int p0 = blockIdx.x * 128;
  const int b = blockIdx.z;
  const int wm = (w >> 1) * 64, wn = (w & 1) * 64;
  f32x4 acc[4][4] = {};
  const float* xb = x + (size_t)b * 256 * HWN;
  const int srow = l >> 2, scol = (l & 3) * 8;
  for (int k0 = 0; k0 < 256; k0 += 32) {
    __syncthreads();
    gl_lds16(Wb + (size_t)((w * 2) * 16 + srow) * 256 + k0 + scol, &sm.s.As[(w * 2) * 16 * 32]);
    gl_lds16(Wb + (size_t)((w * 2 + 1) * 16 + srow) * 256 + k0 + scol, &sm.s.As[(w * 2 + 1) * 16 * 32]);
#pragma unroll
    for (int pass = 0; pass < 8; ++pass) {
      int idx = pass * 256 + t;
      int p_l = idx & 127, k2 = idx >> 7;
      int k = k0 + 2 * k2;
      float v0 = xb[(size_t)k * HWN + p0 + p_l];
      float v1 = xb[(size_t)(k + 1) * HWN + p0 + p_l];
      sm.s.BsU[bs_w(p_l, k2)] = (unsigned)f2bf(v0) | ((unsigned)f2bf(v1) << 16);
    }
    __syncthreads();
    const int q = l >> 4, r16 = l & 15;
    short8 a[4], bv[4];
#pragma unroll
    for (int i = 0; i < 4; ++i)
      a[i] = *reinterpret_cast<const short8*>(&sm.s.As[(wm + i * 16 + r16) * 32 + q * 8]);
#pragma unroll
    for (int j = 0; j < 4; ++j) {
      int row = wn + j * 16 + r16;
      bv[j] = *reinterpret_cast<const short8*>(&sm.s.BsU[bs_r(row, q)]);
    }
#pragma unroll
    for (int i = 0; i < 4; ++i)
#pragma unroll
      for (int j = 0; j < 4; ++j)
        acc[i][j] = __builtin_amdgcn_mfma_f32_16x16x32_bf16(a[i], bv[j], acc[i][j], 0, 0, 0);
  }
  __syncthreads();  // all ds_reads done before Ep overwrites As/Bs
  float* T = sm.Ep + w * (16 * 68);
  const int col = l & 15, rowq = (l >> 4) * 4;
#pragma unroll
  for (int i = 0; i < 4; ++i) {
#pragma unroll
    for (int r = 0; r < 4; ++r)
#pragma unroll
      for (int j = 0; j < 4; ++j)
        T[(rowq + r) * 68 + j * 16 + col] = acc[i][j][r];
#pragma unroll
    for (int pass = 0; pass < 4; ++pass) {
      int row_l = pass * 4 + (l >> 4);
      const float4 v = *reinterpret_cast<const float4*>(&T[row_l * 68 + col * 4]);
      int c = wm + i * 16 + row_l;
      float s = bn[c] * rsqrtf(bn[384 + c] + 1e-5f);
      float tt = bn[128 + c] - bn[256 + c] * s;
      float4 o;
      o.x = siluf(v.x * s + tt);
      o.y = siluf(v.y * s + tt);
      o.z = siluf(v.z * s + tt);
      o.w = siluf(v.w * s + tt);
      float* dst = (c < 64 ? hs : hb) + ((size_t)b * 64 + (c & 63)) * HWN + p0 + wn + col * 4;
      *reinterpret_cast<float4*>(dst) = o;
    }
  }
}

// ---------------- K2: 3x3 offset conv (64->3), 16 ch per barrier round -------
// grid (25, 16), block 256 (16x16 pixel tile)
__global__ __launch_bounds__(256) void k_offset(const float* __restrict__ hs,
    const float* __restrict__ w, const float* __restrict__ bias,
    float* __restrict__ sx, float* __restrict__ sy, float* __restrict__ msk) {
  __shared__ float ht[16 * 324];
  __shared__ float wt[1728];
  const int t = threadIdx.x;
  const int b = blockIdx.y;
  const int x0 = (blockIdx.x % 5) * 16, y0 = (blockIdx.x / 5) * 16;
  const int lx = t & 15, ly = t >> 4;
  for (int i = t; i < 1728; i += 256) wt[i] = w[i];
  float a0 = 0.f, a1 = 0.f, a2 = 0.f;
  for (int r = 0; r < 4; ++r) {
    __syncthreads();
    for (int i = t; i < 16 * 324; i += 256) {
      int ch = i / 324, pos = i - ch * 324;
      int iy = pos / 18, ix = pos - iy * 18;
      int gy = y0 + iy - 1, gx = x0 + ix - 1;
      ht[i] = ((unsigned)gy < (unsigned)HH && (unsigned)gx < (unsigned)WW)
                  ? hs[((size_t)b * 64 + r * 16 + ch) * HWN + gy * WW + gx] : 0.f;
    }
    __syncthreads();
    for (int ch = 0; ch < 16; ++ch) {
      const float* base = &ht[ch * 324];
      const int c = r * 16 + ch;
#pragma unroll
      for (int dy = 0; dy < 3; ++dy)
#pragma unroll
        for (int dx = 0; dx < 3; ++dx) {
          float v = base[(ly + dy) * 18 + lx + dx];
          a0 = fmaf(wt[c * 9 + dy * 3 + dx], v, a0);
          a1 = fmaf(wt[576 + c * 9 + dy * 3 + dx], v, a1);
          a2 = fmaf(wt[1152 + c * 9 + dy * 3 + dx], v, a2);
        }
    }
  }
  a0 += bias[0];
  a1 += bias[1];
  a2 += bias[2];
  size_t o = (size_t)b * HWN + (y0 + ly) * WW + x0 + lx;
  const float sc = 79.f / 80.f;
  sx[o] = (float)(x0 + lx) + a1 * sc;
  sy[o] = (float)(y0 + ly) + a0 * sc;
  msk[o] = sigf(a2);
}

// ---------------- K3: fused bilinear sample*mask + depthwise 3x3 -------------
__global__ __launch_bounds__(256) void k_gsdw(const float* __restrict__ hs,
    const float* __restrict__ sx, const float* __restrict__ sy,
    const float* __restrict__ msk, const float* __restrict__ wdw,
    float* __restrict__ outp) {
  __shared__ float tile[18 * 18];
  const int t = threadIdx.x;
  const int c = blockIdx.y, b = blockIdx.z;
  const int tx0 = (blockIdx.x % 5) * 16, ty0 = (blockIdx.x / 5) * 16;
  const float* pl = hs + ((size_t)b * 64 + c) * HWN;
  for (int i = t; i < 324; i += 256) {
    int iy = i / 18, ix = i - iy * 18;
    int gy = ty0 + iy - 1, gx = tx0 + ix - 1;
    float v = 0.f;
    if ((unsigned)gy < (unsigned)HH && (unsigned)gx < (unsigned)WW) {
      size_t o = (size_t)b * HWN + gy * WW + gx;
      float gxs = sx[o], gys = sy[o], m = msk[o];
      float x0f = floorf(gxs), y0f = floorf(gys);
      float wx = gxs - x0f, wy = gys - y0f;
      int ix0 = (int)x0f, iy0 = (int)y0f;
      int ix1 = ix0 + 1, iy1 = iy0 + 1;
      float acc = 0.f;
      if ((unsigned)iy0 < (unsigned)HH && (unsigned)ix0 < (unsigned)WW) acc = fmaf(pl[iy0 * WW + ix0], (1.f - wx) * (1.f - wy), acc);
      if ((unsigned)iy0 < (unsigned)HH && (unsigned)ix1 < (unsigned)WW) acc = fmaf(pl[iy0 * WW + ix1], wx * (1.f - wy), acc);
      if ((unsigned)iy1 < (unsigned)HH && (unsigned)ix0 < (unsigned)WW) acc = fmaf(pl[iy1 * WW + ix0], (1.f - wx) * wy, acc);
      if ((unsigned)iy1 < (unsigned)HH && (unsigned)ix1 < (unsigned)WW) acc = fmaf(pl[iy1 * WW + ix1], wx * wy, acc);
      v = acc * m;
    }
    tile[i] = v;
  }
  __syncthreads();
  const int lx = t & 15, ly = t >> 4;
  const float* wc = wdw + c * 9;
  float acc = 0.f;
#pragma unroll
  for (int dy = 0; dy < 3; ++dy)
#pragma unroll
    for (int dx = 0; dx < 3; ++dx)
      acc = fmaf(wc[dy * 3 + dx], tile[(ly + dy) * 18 + lx + dx], acc);
  outp[((size_t)b * 64 + c) * HWN + (ty0 + ly) * WW + tx0 + lx] = acc;
}

// ---------------- K4: MFMA 1x1 conv 64->64 + BN + SiLU -----------------------
// tile 64c x 128p, K=64 in 2 chunks. grid (50, 16), block 256; Ep aliased
__global__ __launch_bounds__(256) void k_pw_mfma(const float* __restrict__ in,
    const ushortT* __restrict__ Wpb, const float* __restrict__ bn,
    float* __restrict__ outp) {
  __shared__ union {
    struct { ushortT As[2][64 * 32]; unsigned BsU[128 * 20]; } s;
    float Ep[4 * 16 * 36];
  } sm;
  const int t = threadIdx.x;
  const int w = t >> 6, l = t & 63;
  const int p0 = blockIdx.x * 128;
  const int b = blockIdx.y;
  const int wn = w * 32;
  f32x4 acc[4][2] = {};
  const int srow = l >> 2, scol = (l & 3) * 8;
  gl_lds16(Wpb + (size_t)(w * 16 + srow) * 64 + scol,      &sm.s.As[0][w * 16 * 32]);
  gl_lds16(Wpb + (size_t)(w * 16 + srow) * 64 + 32 + scol, &sm.s.As[1][w * 16 * 32]);
  for (int kc = 0; kc < 2; ++kc) {
    __syncthreads();
    const int ch0 = kc * 32;
#pragma unroll
    for (int pass = 0; pass < 8; ++pass) {
      int idx = pass * 256 + t;
      int p_l = idx & 127, k2 = idx >> 7;
      int k = ch0 + 2 * k2;
      float v0 = in[((size_t)b * 64 + k) * HWN + p0 + p_l];
      float v1 = in[((size_t)b * 64 + k + 1) * HWN + p0 + p_l];
      sm.s.BsU[bs_w(p_l, k2)] = (unsigned)f2bf(v0) | ((unsigned)f2bf(v1) << 16);
    }
    __syncthreads();
    const int q = l >> 4, r16 = l & 15;
    short8 a[4], bv[2];
#pragma unroll
    for (int i = 0; i < 4; ++i)
      a[i] = *reinterpret_cast<const short8*>(&sm.s.As[kc][(i * 16 + r16) * 32 + q * 8]);
#pragma unroll
    for (int j = 0; j < 2; ++j)
      bv[j] = *reinterpret_cast<const short8*>(&sm.s.BsU[bs_r(wn + j * 16 + r16, q)]);
#pragma unroll
    for (int i = 0; i < 4; ++i)
#pragma unroll
      for (int j = 0; j < 2; ++j)
        acc[i][j] = __builtin_amdgcn_mfma_f32_16x16x32_bf16(a[i], bv[j], acc[i][j], 0, 0, 0);
  }
  __syncthreads();
  float* T = sm.Ep + w * (16 * 36);
  const int col = l & 15, rowq = (l >> 4) * 4;
#pragma unroll
  for (int i = 0; i < 4; ++i) {
#pragma unroll
    for (int r = 0; r < 4; ++r)
#pragma unroll
      for (int j = 0; j < 2; ++j)
        T[(rowq + r) * 36 + j * 16 + col] = acc[i][j][r];
#pragma unroll
    for (int pass = 0; pass < 2; ++pass) {
      int flat = pass * 64 + l;
      int row_l = flat >> 3, c4 = flat & 7;
      const float4 v = *reinterpret_cast<const float4*>(&T[row_l * 36 + c4 * 4]);
      int c = i * 16 + row_l;
      float s = bn[c] * rsqrtf(bn[192 + c] + 1e-5f);
      float tt = bn[64 + c] - bn[128 + c] * s;
      float4 o;
      o.x = siluf(v.x * s + tt);
      o.y = siluf(v.y * s + tt);
      o.z = siluf(v.z * s + tt);
      o.w = siluf(v.w * s + tt);
      *reinterpret_cast<float4*>(outp + ((size_t)b * 64 + c) * HWN + p0 + wn + c4 * 4) = o;
    }
  }
}

// ---------------- K5: fused a1+d2+d3+asym -> ctx; star0; partial cmean -------
__global__ __launch_bounds__(256) void k_ctxstar(const float* __restrict__ hs,
    const float* __restrict__ dcn,
    const float* __restrict__ wd2, const float* __restrict__ bnd2,
    const float* __restrict__ wd3, const float* __restrict__ bnd3,
    const float* __restrict__ wa1, const float* __restrict__ bna1,
    const float* __restrict__ wa2, const float* __restrict__ bna2,
    const float* __restrict__ cw, const float* __restrict__ bnstar,
    float* __restrict__ star0, float* __restrict__ cmean) {
  __shared__ float ht[22 * 23];
  __shared__ float at[22 * 17];
  const int t = threadIdx.x;
  const int c = blockIdx.y, b = blockIdx.z;
  const int tx0 = (blockIdx.x % 5) * 16, ty0 = (blockIdx.x / 5) * 16;
  const float* pl = hs + ((size_t)b * 64 + c) * HWN;
  for (int i = t; i < 484; i += 256) {
    int iy = i / 22, ix = i - iy * 22;
    int gy = ty0 + iy - 3, gx = tx0 + ix - 3;
    ht[iy * 23 + ix] = ((unsigned)gy < (unsigned)HH && (unsigned)gx < (unsigned)WW)
                           ? pl[gy * WW + gx] : 0.f;
  }
  __syncthreads();
  for (int i = t; i < 352; i += 256) {
    int iy = i >> 4, ix = i & 15;
    int gy = ty0 + iy - 3;
    float v = 0.f;
    if ((unsigned)gy < (unsigned)HH) {
      float s = 0.f;
#pragma unroll
      for (int k = 0; k < 7; ++k) s = fmaf(wa1[c * 7 + k], ht[iy * 23 + ix + k], s);
      v = siluf(bnap(s, bna1, c, 64));
    }
    at[iy * 17 + ix] = v;
  }
  __syncthreads();
  const int lx = t & 15, ly = t >> 4;
  float d2 = 0.f, d3 = 0.f;
#pragma unroll
  for (int dy = 0; dy < 3; ++dy)
#pragma unroll
    for (int dx = 0; dx < 3; ++dx) {
      float w2 = wd2[c * 9 + dy * 3 + dx], w3 = wd3[c * 9 + dy * 3 + dx];
      d2 = fmaf(w2, ht[(ly + 3 + 2 * (dy - 1)) * 23 + lx + 3 + 2 * (dx - 1)], d2);
      d3 = fmaf(w3, ht[(ly + 3 + 3 * (dy - 1)) * 23 + lx + 3 + 3 * (dx - 1)], d3);
    }
  float as = 0.f;
#pragma unroll
  for (int k = 0; k < 7; ++k) as = fmaf(wa2[c * 7 + k], at[(ly + k) * 17 + lx], as);
  d2 = siluf(bnap(d2, bnd2, c, 64));
  d3 = siluf(bnap(d3, bnd3, c, 64));
  as = siluf(bnap(as, bna2, c, 64));
  float e0 = __expf(cw[0]), e1 = __expf(cw[1]), e2 = __expf(cw[2]);
  float inv = 1.f / (e0 + e1 + e2);
  float ctx = (e0 * d2 + e1 * d3 + e2 * as) * inv;
  size_t o = ((size_t)b * 64 + c) * HWN + (ty0 + ly) * WW + tx0 + lx;
  float sv = bnap(dcn[o] * ctx, bnstar, c, 64);
  star0[o] = sv;
  // block partial sum -> global channel mean accumulator
  __syncthreads();
  ht[t] = sv;
  __syncthreads();
  for (int st = 128; st > 0; st >>= 1) {
    if (t < st) ht[t] += ht[t + st];
    __syncthreads();
  }
  if (t == 0) atomicAdd(&cmean[b * 64 + c], ht[0]);
}

// ---------------- K6b: ECA + sigmoid (cmean holds raw sums) ------------------
__global__ __launch_bounds__(1024) void k_eca(const float* __restrict__ mean,
    const float* __restrict__ ew, float* __restrict__ ych) {
  const int t = threadIdx.x;
  const int c = t & 63;
  const int base = t - c;
  float acc = 0.f;
#pragma unroll
  for (int k = 0; k < 5; ++k) {
    int cc = c + k - 2;
    if ((unsigned)cc < 64u) acc = fmaf(ew[k], mean[base + cc] * (1.f / HWN), acc);
  }
  ych[t] = sigf(acc);
}

// ---------------- K7: channel mean/max of star0*ych, 4-wave split ------------
__global__ __launch_bounds__(256) void k_spstats(const float* __restrict__ star0,
    const float* __restrict__ ych, float* __restrict__ spmean, float* __restrict__ spmax) {
  __shared__ float yc[64];
  __shared__ float rs[4][64], rm[4][64];
  const int t = threadIdx.x;
  const int b = blockIdx.y;
  const int p0 = blockIdx.x * 64;
  if (t < 64) yc[t] = ych[b * 64 + t];
  __syncthreads();
  const int tq = t >> 6, pix = t & 63;
  float s = 0.f, mx = -1e30f;
  for (int cc = 0; cc < 16; ++cc) {
    int c = tq * 16 + cc;
    float v = star0[((size_t)b * 64 + c) * HWN + p0 + pix] * yc[c];
    s += v;
    mx = fmaxf(mx, v);
  }
  rs[tq][pix] = s;
  rm[tq][pix] = mx;
  __syncthreads();
  if (t < 64) {
    float ss = rs[0][t] + rs[1][t] + rs[2][t] + rs[3][t];
    float mm = fmaxf(fmaxf(rm[0][t], rm[1][t]), fmaxf(rm[2][t], rm[3][t]));
    spmean[(size_t)b * HWN + p0 + t] = ss * (1.f / 64.f);
    spmax[(size_t)b * HWN + p0 + t] = mm;
  }
}

// ---------------- K8: 7x7 conv on [mean,max] -> sigmoid ----------------------
__global__ __launch_bounds__(256) void k_spconv(const float* __restrict__ spmean,
    const float* __restrict__ spmax, const float* __restrict__ w,
    float* __restrict__ spat) {
  const int p = blockIdx.x * 256 + threadIdx.x;
  const int b = blockIdx.y;
  const int y = p / WW, x = p - y * WW;
  const float* me = spmean + (size_t)b * HWN;
  const float* mx = spmax + (size_t)b * HWN;
  float acc = 0.f;
#pragma unroll
  for (int dy = 0; dy < 7; ++dy) {
    int yy = y + dy - 3;
    if ((unsigned)yy >= (unsigned)HH) continue;
#pragma unroll
    for (int dx = 0; dx < 7; ++dx) {
      int xx = x + dx - 3;
      if ((unsigned)xx >= (unsigned)WW) continue;
      acc = fmaf(w[dy * 7 + dx], me[yy * WW + xx], acc);
      acc = fmaf(w[49 + dy * 7 + dx], mx[yy * WW + xx], acc);
    }
  }
  spat[(size_t)b * HWN + p] = sigf(acc);
}

// ---------------- K9: MFMA GEMM 128->256 + BN + SiLU + residual --------------
// grid (50, 2, 16), block 256; Ep aliased over As/Bs
__global__ __launch_bounds__(256) void k_expand_mfma(
    const float* __restrict__ star0, const float* __restrict__ hbuf,
    const float* __restrict__ ych, const float* __restrict__ spat,
    const float* __restrict__ blend, const ushortT* __restrict__ Wb,
    const float* __restrict__ bn, const float* __restrict__ xin,
    float* __restrict__ outp) {
  __shared__ union {
    struct { ushortT As[128 * 32]; unsigned BsU[128 * 20]; } s;
    float Ep[4 * 16 * 68];
  } sm;
  __shared__ float Sp[128];
  __shared__ float Yc[64];
  const int t = threadIdx.x;
  const int w = t >> 6, l = t & 63;
  const int p0 = blockIdx.x * 128;
  const int c0 = blockIdx.y * 128;
  const int b = blockIdx.z;
  const int wm = (w >> 1) * 64, wn = (w & 1) * 64;
  const float alpha = sigf(blend[0]);
  const float beta = 1.f - alpha;
  if (t < 128) Sp[t] = alpha * spat[(size_t)b * HWN + p0 + t];
  else if (t < 192) Yc[t - 128] = ych[b * 64 + (t - 128)];
  f32x4 acc[4][4] = {};
  const int srow = l >> 2, scol = (l & 3) * 8;
  for (int k0 = 0; k0 < 128; k0 += 32) {
    __syncthreads();
    gl_lds16(Wb + (size_t)(c0 + (w * 2) * 16 + srow) * 128 + k0 + scol, &sm.s.As[(w * 2) * 16 * 32]);
    gl_lds16(Wb + (size_t)(c0 + (w * 2 + 1) * 16 + srow) * 128 + k0 + scol, &sm.s.As[(w * 2 + 1) * 16 * 32]);
    const int ch0 = k0 >> 1;
#pragma unroll
    for (int pass = 0; pass < 8; ++pass) {
      int idx = pass * 256 + t;
      int p_l = idx & 127, chl = idx >> 7;
      int ch = ch0 + chl;
      size_t o = ((size_t)b * 64 + ch) * HWN + p0 + p_l;
      float vs = star0[o] * Yc[ch] * Sp[p_l];
      float vh = beta * hbuf[o];
      sm.s.BsU[bs_w(p_l, chl)] = (unsigned)f2bf(vs) | ((unsigned)f2bf(vh) << 16);
    }
    __syncthreads();
    const int q = l >> 4, r16 = l & 15;
    short8 a[4], bv[4];
#pragma unroll
    for (int i = 0; i < 4; ++i)
      a[i] = *reinterpret_cast<const short8*>(&sm.s.As[(wm + i * 16 + r16) * 32 + q * 8]);
#pragma unroll
    for (int j = 0; j < 4; ++j) {
      int row = wn + j * 16 + r16;
      bv[j] = *reinterpret_cast<const short8*>(&sm.s.BsU[bs_r(row, q)]);
    }
#pragma unroll
    for (int i = 0; i < 4; ++i)
#pragma unroll
      for (int j = 0; j < 4; ++j)
        acc[i][j] = __builtin_amdgcn_mfma_f32_16x16x32_bf16(a[i], bv[j], acc[i][j], 0, 0, 0);
  }
  __syncthreads();
  float* T = sm.Ep + w * (16 * 68);
  const int col = l & 15, rowq = (l >> 4) * 4;
#pragma unroll
  for (int i = 0; i < 4; ++i) {
#pragma unroll
    for (int r = 0; r < 4; ++r)
#pragma unroll
      for (int j = 0; j < 4; ++j)
        T[(rowq + r) * 68 + j * 16 + col] = acc[i][j][r];
#pragma unroll
    for (int pass = 0; pass < 4; ++pass) {
      int row_l = pass * 4 + (l >> 4);
      const float4 v = *reinterpret_cast<const float4*>(&T[row_l * 68 + col * 4]);
      int c = c0 + wm + i * 16 + row_l;
      float s = bn[c] * rsqrtf(bn[768 + c] + 1e-5f);
      float tt = bn[256 + c] - bn[512 + c] * s;
      size_t o = ((size_t)b * 256 + c) * HWN + p0 + wn + col * 4;
      const float4 xr = *reinterpret_cast<const float4*>(xin + o);
      float4 ov;
      ov.x = siluf(v.x * s + tt) + xr.x;
      ov.y = siluf(v.y * s + tt) + xr.y;
      ov.z = siluf(v.z * s + tt) + xr.z;
      ov.w = siluf(v.w * s + tt) + xr.w;
      *reinterpret_cast<float4*>(outp + o) = ov;
    }
  }
}

extern "C" void kernel_launch(void* const* d_in, const int* in_sizes, int n_in,
                              void* d_out, int out_size, void* d_ws, size_t ws_size,
                              hipStream_t stream) {
  const float* x         = (const float*)d_in[0];
  const float* w_reduce  = (const float*)d_in[1];
  const float* bn_reduce = (const float*)d_in[2];
  const float* dcn_off_w = (const float*)d_in[3];
  const float* dcn_off_b = (const float*)d_in[4];
  const float* dcn_dw_w  = (const float*)d_in[5];
  const float* dcn_pw_w  = (const float*)d_in[6];
  const float* bn_dcn    = (const float*)d_in[7];
  const float* w_d2      = (const float*)d_in[8];
  const float* bn_d2     = (const float*)d_in[9];
  const float* w_d3      = (const float*)d_in[10];
  const float* bn_d3     = (const float*)d_in[11];
  const float* w_asym1   = (const float*)d_in[12];
  const float* bn_asym1  = (const float*)d_in[13];
  const float* w_asym2   = (const float*)d_in[14];
  const float* bn_asym2  = (const float*)d_in[15];
  const float* ctx_w     = (const float*)d_in[16];
  const float* bn_star   = (const float*)d_in[17];
  const float* eca_w     = (const float*)d_in[18];
  const float* sp_w      = (const float*)d_in[19];
  const float* blend     = (const float*)d_in[20];
  const float* w_expand  = (const float*)d_in[21];
  const float* bn_expand = (const float*)d_in[22];
  float* out = (float*)d_out;
  float* ws = (float*)d_ws;

  float* slotA = ws;                    // hs
  float* slotB = ws + BIGN;             // hb
  float* slotC = ws + 2 * BIGN;         // dw output
  float* slotD = ws + 3 * BIGN;         // dcn, then star0 (in-place)
  float* sm = ws + 4 * BIGN;
  float* sx     = sm;                   // alias spmean (disjoint lifetime)
  float* sy     = sm + 102400;          // alias spmax
  float* msk    = sm + 204800;          // alias spat
  float* spmean = sx;
  float* spmax  = sy;
  float* spat   = msk;
  float* cmean  = sm + 307200;
  float* ych    = sm + 308224;
  ushortT* Wrb = (ushortT*)(sm + 309248);
  ushortT* Web = Wrb + 32768;
  ushortT* Wpb = Web + 32768;

  k_cvtw<<<dim3(272), 256, 0, stream>>>(w_reduce, w_expand, dcn_pw_w, Wrb, Web, Wpb, cmean);
  k_reduce_mfma<<<dim3(50, 1, 16), 256, 0, stream>>>(x, Wrb, bn_reduce, slotA, slotB);
  k_offset<<<dim3(25, 16), 256, 0, stream>>>(slotA, dcn_off_w, dcn_off_b, sx, sy, msk);
  k_gsdw<<<dim3(25, 64, 16), 256, 0, stream>>>(slotA, sx, sy, msk, dcn_dw_w, slotC);
  k_pw_mfma<<<dim3(50, 16), 256, 0, stream>>>(slotC, Wpb, bn_dcn, slotD);
  k_ctxstar<<<dim3(25, 64, 16), 256, 0, stream>>>(slotA, slotD, w_d2, bn_d2,
                                                  w_d3, bn_d3, w_asym1, bn_asym1,
                                                  w_asym2, bn_asym2, ctx_w, bn_star,
                                                  slotD, cmean);
  k_eca<<<dim3(1), 1024, 0, stream>>>(cmean, eca_w, ych);
  k_spstats<<<dim3(100, 16), 256, 0, stream>>>(slotD, ych, spmean, spmax);
  k_spconv<<<dim3(25, 16), 256, 0, stream>>>(spmean, spmax, sp_w, spat);
  k_expand_mfma<<<dim3(50, 2, 16), 256, 0, stream>>>(slotD, slotB, ych, spat, blend,
                                                     Web, bn_expand, x, out);
}